// Round 1
// 517.240 us; speedup vs baseline: 1.0410x; 1.0410x over previous
//
#include <hip/hip_runtime.h>
#include <hip/hip_bf16.h>
#include <stdint.h>

// ---------- types ----------
typedef __bf16 bf16x8 __attribute__((ext_vector_type(8)));
typedef float floatx4 __attribute__((ext_vector_type(4)));

__device__ __forceinline__ ushort f2bf(float f) {
  union { float f; uint32_t u; } v; v.f = f;
  uint32_t r = (v.u + 0x7fffu + ((v.u >> 16) & 1u)) >> 16;
  return (ushort)r;
}

__device__ __forceinline__ void load_lds16(const ushort* g, ushort* l) {
  __builtin_amdgcn_global_load_lds(
      (__attribute__((address_space(1))) void*)g,
      (__attribute__((address_space(3))) void*)l, 16, 0, 0);
}

__device__ __forceinline__ float leaky(float x) { return x >= 0.f ? x : 0.01f * x; }

// ---------- kernel 1: fused two-stream LayerNorm + leaky_relu -> bf16 f[B,1536] ----------
// wave-per-row: no LDS, no __syncthreads, 4x fewer shuffle-lane-ops than block-per-row.
__global__ __launch_bounds__(256) void ln2_kernel(
    const float* __restrict__ x1, const float* __restrict__ x2,
    const float* __restrict__ sc1p, const float* __restrict__ bi1p,
    const float* __restrict__ sc2p, const float* __restrict__ bi2p,
    ushort* __restrict__ f) {
  const int row = (blockIdx.x << 2) + (threadIdx.x >> 6);
  const int lane = threadIdx.x & 63;
  const float4* X1 = (const float4*)(x1 + (size_t)row * 1024);
  const float4* X2 = (const float4*)(x2 + (size_t)row * 512);
  float4 v1[4], v2[2];
#pragma unroll
  for (int j = 0; j < 4; j++) v1[j] = X1[j * 64 + lane];
#pragma unroll
  for (int j = 0; j < 2; j++) v2[j] = X2[j * 64 + lane];
  float s1 = 0.f, q1 = 0.f, s2 = 0.f, q2 = 0.f;
#pragma unroll
  for (int j = 0; j < 4; j++) {
    s1 += v1[j].x + v1[j].y + v1[j].z + v1[j].w;
    q1 += v1[j].x * v1[j].x + v1[j].y * v1[j].y + v1[j].z * v1[j].z + v1[j].w * v1[j].w;
  }
#pragma unroll
  for (int j = 0; j < 2; j++) {
    s2 += v2[j].x + v2[j].y + v2[j].z + v2[j].w;
    q2 += v2[j].x * v2[j].x + v2[j].y * v2[j].y + v2[j].z * v2[j].z + v2[j].w * v2[j].w;
  }
#pragma unroll
  for (int o = 1; o < 64; o <<= 1) {
    s1 += __shfl_xor(s1, o);
    q1 += __shfl_xor(q1, o);
    s2 += __shfl_xor(s2, o);
    q2 += __shfl_xor(q2, o);
  }
  const float m1 = s1 * (1.0f / 1024.0f);
  const float r1 = rsqrtf(q1 * (1.0f / 1024.0f) - m1 * m1 + 1e-6f);
  const float m2 = s2 * (1.0f / 512.0f);
  const float r2 = rsqrtf(q2 * (1.0f / 512.0f) - m2 * m2 + 1e-6f);
  ushort* frow = f + (size_t)row * 1536;
#pragma unroll
  for (int j = 0; j < 4; j++) {
    const float4 sc = ((const float4*)sc1p)[j * 64 + lane];
    const float4 bi = ((const float4*)bi1p)[j * 64 + lane];
    const float y0 = leaky((v1[j].x - m1) * r1 * sc.x + bi.x);
    const float y1 = leaky((v1[j].y - m1) * r1 * sc.y + bi.y);
    const float y2 = leaky((v1[j].z - m1) * r1 * sc.z + bi.z);
    const float y3 = leaky((v1[j].w - m1) * r1 * sc.w + bi.w);
    ushort4 o; o.x = f2bf(y0); o.y = f2bf(y1); o.z = f2bf(y2); o.w = f2bf(y3);
    ((ushort4*)frow)[j * 64 + lane] = o;
  }
#pragma unroll
  for (int j = 0; j < 2; j++) {
    const float4 sc = ((const float4*)sc2p)[j * 64 + lane];
    const float4 bi = ((const float4*)bi2p)[j * 64 + lane];
    const float z0 = leaky((v2[j].x - m2) * r2 * sc.x + bi.x);
    const float z1 = leaky((v2[j].y - m2) * r2 * sc.y + bi.y);
    const float z2 = leaky((v2[j].z - m2) * r2 * sc.z + bi.z);
    const float z3 = leaky((v2[j].w - m2) * r2 * sc.w + bi.w);
    ushort4 o; o.x = f2bf(z0); o.y = f2bf(z1); o.z = f2bf(z2); o.w = f2bf(z3);
    ((ushort4*)(frow + 1024))[j * 64 + lane] = o;
  }
}

// ---------- kernel 2: weight transpose + cast -> WcatT[2048][1536] bf16 ----------
// source col j, within-64 c=j&63, stream s: n_local = (c>>5)*64 + s*32 + ((c>>4)&1)*16 + (c&15)
// so each 64-col window of permuted N is [S 0-15 | S 16-31 | G 0-15 | G 16-31] of the same out cols.
__global__ __launch_bounds__(256) void wprep_kernel(
    const float* __restrict__ Wo1, const float* __restrict__ Wo2,
    const float* __restrict__ Wg1, const float* __restrict__ Wg2,
    ushort* __restrict__ WT) {
  __shared__ float tile[32][33];
  const int k0 = blockIdx.x * 32;  // 48
  const int j0 = blockIdx.y * 32;  // 32
  const int s = blockIdx.z;        // 2
  const float* Wa = s ? Wg1 : Wo1;
  const float* Wb = s ? Wg2 : Wo2;
  const int tx = threadIdx.x;  // 0..31
  const int ty = threadIdx.y;  // 0..7
#pragma unroll
  for (int r = 0; r < 4; r++) {
    const int k = k0 + ty + 8 * r;
    const float val = (k < 1024) ? Wa[(size_t)k * 1024 + j0 + tx]
                                 : Wb[(size_t)(k - 1024) * 1024 + j0 + tx];
    tile[ty + 8 * r][tx] = val;
  }
  __syncthreads();
#pragma unroll
  for (int r = 0; r < 4; r++) {
    const int j = j0 + ty + 8 * r;
    const int c = j & 63;
    const int n = (j >> 6) * 128 + (c >> 5) * 64 + s * 32 + ((c >> 4) & 1) * 16 + (c & 15);
    WT[(size_t)n * 1536 + k0 + tx] = f2bf(tile[tx][ty + 8 * r]);
  }
}

// ---------- kernel 3: 256x256 8-phase GEMM [32768x1536]x[1536x2048] + bias + sigmoid-gate ----------
// 512 threads = 8 waves (2M x 4N), wave tile 128x64, BK=64, depth-1 LDS double buffer (128 KiB).
// T2: 16B chunk c of LDS row r lives at phys chunk c^(r&7); staged via pre-swizzled global src.
// T3/T4: 4 phases per K-tile, staging issued phases 0-1, single counted drain at phase-3 boundary.
// T5: setprio around each 16-MFMA cluster. T1: XCD swizzle (1024 wgs, 8 | 1024 -> bijective).
__global__ __launch_bounds__(512, 2) void gemm_fused(
    const ushort* __restrict__ A,   // f [32768][1536] bf16
    const ushort* __restrict__ Bt,  // WcatT [2048][1536] bf16
    const float* __restrict__ bo1, const float* __restrict__ bo2,
    const float* __restrict__ bg1, const float* __restrict__ bg2,
    float* __restrict__ out) {      // [32768][1024] f32
  __shared__ __align__(16) ushort As[2][16384];
  __shared__ __align__(16) ushort Bs[2][16384];
  const int orig = blockIdx.x;
  const int swz = (orig & 7) * 128 + (orig >> 3);  // XCD-contiguous
  const int mt = swz >> 3;  // 0..127 : each XCD owns 16 consecutive A panels
  const int nt = swz & 7;   // 0..7   : B panels (6 MB total) L2-resident per XCD
  const int tid = threadIdx.x;
  const int wave = tid >> 6, lane = tid & 63;
  const int wr = wave >> 2, wcol = wave & 3;
  const int low = lane & 15, quad = lane >> 4;

  // staging: lane covers (row = wave*8 + lane>>3, phys chunk = lane&7); global src pre-swizzled
  const int srow = wave * 8 + (lane >> 3);
  const int schunk = (lane & 7) ^ (lane >> 3);
  const ushort* gA0 = A + ((size_t)mt * 256 + srow) * 1536 + schunk * 8;
  const ushort* gB0 = Bt + ((size_t)nt * 256 + srow) * 1536 + schunk * 8;

  // frag read offsets: row = base + m*16 + low (m*16 == 0 mod 8 -> swizzle key is low&7)
  const int q2 = quad ^ (low & 3);
  const int kx = (low >> 2) & 1;
  const int offA_k0 = (wr * 128 + low) * 64 + (q2 + 4 * kx) * 8;
  const int offA_k1 = (wr * 128 + low) * 64 + (q2 + 4 * (1 - kx)) * 8;
  const int offB_k0 = (wcol * 64 + low) * 64 + (q2 + 4 * kx) * 8;
  const int offB_k1 = (wcol * 64 + low) * 64 + (q2 + 4 * (1 - kx)) * 8;

  floatx4 acc[8][4];
#pragma unroll
  for (int m = 0; m < 8; m++)
#pragma unroll
    for (int n = 0; n < 4; n++) acc[m][n] = (floatx4)0.0f;

#define STAGE_A(BUF, KT) do { \
    const ushort* s_ = gA0 + (KT) * 64; \
    ushort* d_ = &As[BUF][wave * 512]; \
    load_lds16(s_, d_); \
    load_lds16(s_ + 64 * 1536, d_ + 4096); \
    load_lds16(s_ + 128 * 1536, d_ + 8192); \
    load_lds16(s_ + 192 * 1536, d_ + 12288); \
  } while (0)
#define STAGE_B(BUF, KT) do { \
    const ushort* s_ = gB0 + (KT) * 64; \
    ushort* d_ = &Bs[BUF][wave * 512]; \
    load_lds16(s_, d_); \
    load_lds16(s_ + 64 * 1536, d_ + 4096); \
    load_lds16(s_ + 128 * 1536, d_ + 8192); \
    load_lds16(s_ + 192 * 1536, d_ + 12288); \
  } while (0)

  // prologue: tile 0 -> buf 0
  STAGE_A(0, 0);
  STAGE_B(0, 0);
  asm volatile("s_waitcnt vmcnt(0)" ::: "memory");
  __builtin_amdgcn_s_barrier();
  asm volatile("" ::: "memory");

#define TILE_STEP(CUR, T) do { \
    const ushort* Ac = &As[CUR][0]; \
    const ushort* Bc = &Bs[CUR][0]; \
    const bool pf = (T) < 23; \
    bf16x8 a[4], b[4]; \
    /* ---- PH0: A m0-3 k0 + B k0 reads; stage A(t+1) ---- */ \
    _Pragma("unroll") for (int m = 0; m < 4; m++) a[m] = *(const bf16x8*)(Ac + offA_k0 + m * 1024); \
    _Pragma("unroll") for (int n = 0; n < 4; n++) b[n] = *(const bf16x8*)(Bc + offB_k0 + n * 1024); \
    if (pf) STAGE_A((CUR) ^ 1, (T) + 1); \
    asm volatile("" ::: "memory"); \
    __builtin_amdgcn_s_barrier(); \
    __builtin_amdgcn_s_setprio(1); \
    _Pragma("unroll") for (int m = 0; m < 4; m++) \
      _Pragma("unroll") for (int n = 0; n < 4; n++) \
        acc[m][n] = __builtin_amdgcn_mfma_f32_16x16x32_bf16(a[m], b[n], acc[m][n], 0, 0, 0); \
    __builtin_amdgcn_s_setprio(0); \
    asm volatile("" ::: "memory"); \
    __builtin_amdgcn_s_barrier(); \
    /* ---- PH1: A m4-7 k0 reads; stage B(t+1) ---- */ \
    _Pragma("unroll") for (int m = 0; m < 4; m++) a[m] = *(const bf16x8*)(Ac + offA_k0 + (m + 4) * 1024); \
    if (pf) STAGE_B((CUR) ^ 1, (T) + 1); \
    asm volatile("" ::: "memory"); \
    __builtin_amdgcn_s_barrier(); \
    __builtin_amdgcn_s_setprio(1); \
    _Pragma("unroll") for (int m = 0; m < 4; m++) \
      _Pragma("unroll") for (int n = 0; n < 4; n++) \
        acc[m + 4][n] = __builtin_amdgcn_mfma_f32_16x16x32_bf16(a[m], b[n], acc[m + 4][n], 0, 0, 0); \
    __builtin_amdgcn_s_setprio(0); \
    asm volatile("" ::: "memory"); \
    __builtin_amdgcn_s_barrier(); \
    /* ---- PH2: A m0-3 k1 + B k1 reads ---- */ \
    _Pragma("unroll") for (int m = 0; m < 4; m++) a[m] = *(const bf16x8*)(Ac + offA_k1 + m * 1024); \
    _Pragma("unroll") for (int n = 0; n < 4; n++) b[n] = *(const bf16x8*)(Bc + offB_k1 + n * 1024); \
    asm volatile("" ::: "memory"); \
    __builtin_amdgcn_s_barrier(); \
    __builtin_amdgcn_s_setprio(1); \
    _Pragma("unroll") for (int m = 0; m < 4; m++) \
      _Pragma("unroll") for (int n = 0; n < 4; n++) \
        acc[m][n] = __builtin_amdgcn_mfma_f32_16x16x32_bf16(a[m], b[n], acc[m][n], 0, 0, 0); \
    __builtin_amdgcn_s_setprio(0); \
    asm volatile("" ::: "memory"); \
    __builtin_amdgcn_s_barrier(); \
    /* ---- PH3: A m4-7 k1 reads; boundary: drain tile t+1's loads ---- */ \
    _Pragma("unroll") for (int m = 0; m < 4; m++) a[m] = *(const bf16x8*)(Ac + offA_k1 + (m + 4) * 1024); \
    asm volatile("" ::: "memory"); \
    __builtin_amdgcn_s_barrier(); \
    __builtin_amdgcn_s_setprio(1); \
    _Pragma("unroll") for (int m = 0; m < 4; m++) \
      _Pragma("unroll") for (int n = 0; n < 4; n++) \
        acc[m + 4][n] = __builtin_amdgcn_mfma_f32_16x16x32_bf16(a[m], b[n], acc[m + 4][n], 0, 0, 0); \
    __builtin_amdgcn_s_setprio(0); \
    asm volatile("s_waitcnt vmcnt(0)" ::: "memory"); \
    __builtin_amdgcn_s_barrier(); \
    asm volatile("" ::: "memory"); \
  } while (0)

  for (int tt = 0; tt < 12; tt++) {
    TILE_STEP(0, 2 * tt);
    TILE_STEP(1, 2 * tt + 1);
  }
#undef TILE_STEP
#undef STAGE_A
#undef STAGE_B

  // epilogue: frag n in {0,1} = S, frag n+2 = G of the same out columns
  const int colbase = (nt * 4 + wcol) << 5;
#pragma unroll
  for (int n = 0; n < 2; n++) {
    const int col = colbase + n * 16 + low;
    const float bs = bo1[col] + bo2[col];
    const float bg = bg1[col] + bg2[col];
#pragma unroll
    for (int m = 0; m < 8; m++) {
      const floatx4 S = acc[m][n];
      const floatx4 G = acc[m][n + 2];
      const size_t rb = (size_t)mt * 256 + wr * 128 + m * 16 + quad * 4;
#pragma unroll
      for (int r = 0; r < 4; r++) {
        const float sv = S[r] + bs;
        const float gv = G[r] + bg;
        const float gate = 1.0f / (1.0f + __expf(-gv));
        out[(rb + r) * 1024 + col] = gate * sv;
      }
    }
  }
}

extern "C" void kernel_launch(void* const* d_in, const int* in_sizes, int n_in,
                              void* d_out, int out_size, void* d_ws, size_t ws_size,
                              hipStream_t stream) {
  const float* x1 = (const float*)d_in[0];
  const float* x2 = (const float*)d_in[1];
  const float* ln_s1 = (const float*)d_in[2];
  const float* ln_b1 = (const float*)d_in[3];
  const float* ln_s2 = (const float*)d_in[4];
  const float* ln_b2 = (const float*)d_in[5];
  const float* W_out1 = (const float*)d_in[6];
  const float* b_out1 = (const float*)d_in[7];
  const float* W_out2 = (const float*)d_in[8];
  const float* b_out2 = (const float*)d_in[9];
  const float* W_g1 = (const float*)d_in[10];
  const float* b_g1 = (const float*)d_in[11];
  const float* W_g2 = (const float*)d_in[12];
  const float* b_g2 = (const float*)d_in[13];
  float* out = (float*)d_out;

  ushort* f = (ushort*)d_ws;              // [32768][1536] bf16
  ushort* WT = f + (size_t)32768 * 1536;  // [2048][1536] bf16

  ln2_kernel<<<8192, 256, 0, stream>>>(x1, x2, ln_s1, ln_b1, ln_s2, ln_b2, f);
  wprep_kernel<<<dim3(48, 32, 2), dim3(32, 8), 0, stream>>>(W_out1, W_out2, W_g1, W_g2, WT);
  gemm_fused<<<dim3(1024), dim3(512), 0, stream>>>(f, WT, b_out1, b_out2, b_g1, b_g2, out);
}